// Round 1
// baseline (476.587 us; speedup 1.0000x reference)
//
#include <hip/hip_runtime.h>
#include <hip/hip_bf16.h>
#include <stdint.h>
#include <stddef.h>

// MoE: T=4096 tokens, D=1024, H=4096, E=8, top-2. fp32 in/out, bf16 MFMA inside.

#define T_TOK 4096
#define DIM   1024
#define HID   4096
#define NE    8

typedef unsigned short u16;
typedef __bf16 bf16x8 __attribute__((ext_vector_type(8)));
typedef float  f32x4  __attribute__((ext_vector_type(4)));
typedef u16    u16x8  __attribute__((ext_vector_type(8)));

__device__ __forceinline__ u16 f2bf(float f) {
  union { float f; uint32_t u; } v; v.f = f;
  uint32_t u = v.u;
  return (u16)((u + 0x7fffu + ((u >> 16) & 1u)) >> 16);   // RNE
}

__device__ __forceinline__ void async_load16(const void* g, void* l) {
  typedef __attribute__((address_space(1))) void GPtr;
  typedef __attribute__((address_space(3))) void LPtr;
  __builtin_amdgcn_global_load_lds((GPtr*)g, (LPtr*)l, 16, 0, 0);
}

// ---------------- Router: logits -> top2 -> softmax -> expert lists ----------
__global__ void router_kernel(const float* __restrict__ x, const float* __restrict__ Wr,
                              const float* __restrict__ br, const float* __restrict__ gb,
                              int* __restrict__ counts, int* __restrict__ lists,
                              float* __restrict__ gate_p) {
  const int t = blockIdx.x * 4 + (threadIdx.x >> 6);
  const int lane = threadIdx.x & 63;
  const float* xr = x + (size_t)t * DIM;
  float acc[NE];
#pragma unroll
  for (int e = 0; e < NE; ++e) acc[e] = 0.f;
#pragma unroll
  for (int i = 0; i < DIM / 64; ++i) {
    const int k = i * 64 + lane;
    const float xv = xr[k];
    const float4 w0 = *reinterpret_cast<const float4*>(Wr + (size_t)k * NE);
    const float4 w1 = *reinterpret_cast<const float4*>(Wr + (size_t)k * NE + 4);
    acc[0] += xv * w0.x; acc[1] += xv * w0.y; acc[2] += xv * w0.z; acc[3] += xv * w0.w;
    acc[4] += xv * w1.x; acc[5] += xv * w1.y; acc[6] += xv * w1.z; acc[7] += xv * w1.w;
  }
#pragma unroll
  for (int off = 32; off >= 1; off >>= 1) {
#pragma unroll
    for (int e = 0; e < NE; ++e) acc[e] += __shfl_xor(acc[e], off);
  }
  if (lane == 0) {
    float lg[NE];
#pragma unroll
    for (int e = 0; e < NE; ++e) lg[e] = acc[e] + br[e] + gb[e];
    int i0 = 0;
#pragma unroll
    for (int e = 1; e < NE; ++e) if (lg[e] > lg[i0]) i0 = e;
    int i1 = (i0 == 0) ? 1 : 0;
#pragma unroll
    for (int e = 0; e < NE; ++e) if (e != i0 && lg[e] > lg[i1]) i1 = e;
    const float ev = expf(lg[i1] - lg[i0]);         // <= 1
    const float p0 = 1.f / (1.f + ev);
    const float p1 = ev / (1.f + ev);
    const int pos0 = atomicAdd(&counts[i0], 1);
    lists[i0 * T_TOK + pos0] = t * 2 + 0;
    const int pos1 = atomicAdd(&counts[i1], 1);
    lists[i1 * T_TOK + pos1] = t * 2 + 1;
    gate_p[t * 2 + 0] = p0;
    gate_p[t * 2 + 1] = p1;
  }
}

// ---------------- fp32 -> bf16 elementwise (x) -------------------------------
__global__ void cvt_x_kernel(const float* __restrict__ in, u16* __restrict__ out, int n8) {
  const int i = blockIdx.x * blockDim.x + threadIdx.x;
  if (i >= n8) return;
  const float4 a = reinterpret_cast<const float4*>(in)[2 * i];
  const float4 b = reinterpret_cast<const float4*>(in)[2 * i + 1];
  u16x8 r;
  r[0] = f2bf(a.x); r[1] = f2bf(a.y); r[2] = f2bf(a.z); r[3] = f2bf(a.w);
  r[4] = f2bf(b.x); r[5] = f2bf(b.y); r[6] = f2bf(b.z); r[7] = f2bf(b.w);
  *reinterpret_cast<u16x8*>(out + (size_t)i * 8) = r;
}

// ---------------- fp32 [E][K][N] -> bf16 [E][N][K] (transpose-convert) -------
__global__ void cvt_w_kernel(const float* __restrict__ in, u16* __restrict__ out,
                             int K, int N) {
  __shared__ float tile[64][65];
  const int e = blockIdx.z;
  const int n0 = blockIdx.x * 64, k0 = blockIdx.y * 64;
  const int tid = threadIdx.x;
  const float* src = in + (size_t)e * K * N;
#pragma unroll
  for (int r = 0; r < 16; ++r) {
    const int kr = r * 4 + (tid >> 6);
    tile[kr][tid & 63] = src[(size_t)(k0 + kr) * N + n0 + (tid & 63)];
  }
  __syncthreads();
  u16* dst = out + (size_t)e * N * K;
#pragma unroll
  for (int r = 0; r < 8; ++r) {
    const int nr = r * 8 + (tid >> 5);
    const int kc = (tid & 31) * 2;
    ushort2 v;
    v.x = f2bf(tile[kc][nr]);
    v.y = f2bf(tile[kc + 1][nr]);
    *reinterpret_cast<ushort2*>(&dst[(size_t)(n0 + nr) * K + k0 + kc]) = v;
  }
}

// ---------------- Grouped GEMM: 128x128 tile, BK=64, 4 waves -----------------
// PHASE 1: A = xb[t] gather (t=p>>1), B = W1t, out = h[p] = gelu(acc+b1) bf16
// PHASE 2: A = h[p] gather,            B = W2t, out = ypair[p] = g*(acc+b2) f32
// PHASE 3: like 2 but atomicAdd into d_out directly
template <int KT, int NT, int PHASE>
__global__ __launch_bounds__(256, 2)
void gemm_kernel(const u16* __restrict__ Abase, const u16* __restrict__ Bt,
                 const float* __restrict__ bias, const int* __restrict__ counts,
                 const int* __restrict__ lists, const float* __restrict__ gate_p,
                 u16* __restrict__ hout, float* __restrict__ yout) {
  const int e = blockIdx.z;
  const int cnt = counts[e];
  const int m0 = blockIdx.y * 128;
  if (m0 >= cnt) return;
  const int n0 = blockIdx.x * 128;
  const int tid = threadIdx.x;
  const int lane = tid & 63, wid = tid >> 6;
  const int wr = wid >> 1, wc = wid & 1;

  __shared__ alignas(16) u16 As[128 * 72];   // +8 pad: conflict-lite ds_read_b128
  __shared__ alignas(16) u16 Bs[128 * 64];   // linear (global_load_lds dest)
  __shared__ int rowp[128];

  if (tid < 128) {
    const int idx = m0 + tid;
    rowp[tid] = lists[e * T_TOK + (idx < cnt ? idx : cnt - 1)];
  }
  __syncthreads();

  const u16* aptr[4];
#pragma unroll
  for (int i = 0; i < 4; ++i) {
    const int r = i * 32 + (tid >> 3);
    const int p = rowp[r];
    const int arow = (PHASE == 1) ? (p >> 1) : p;
    aptr[i] = Abase + (size_t)arow * KT + (tid & 7) * 8;
  }
  const u16* bsrc = Bt + ((size_t)e * NT + n0) * KT;

  f32x4 acc[4][4];
#pragma unroll
  for (int a = 0; a < 4; ++a)
#pragma unroll
    for (int b = 0; b < 4; ++b) acc[a][b] = f32x4{0.f, 0.f, 0.f, 0.f};

  for (int k0 = 0; k0 < KT; k0 += 64) {
    // B tile: [n=128][k=64] bf16, 4 wave-issues of 1024B each
#pragma unroll
    for (int j = 0; j < 4; ++j) {
      const int brow = j * 32 + wid * 8;
      const u16* src = bsrc + (size_t)(brow + (lane >> 3)) * KT + k0 + (lane & 7) * 8;
      async_load16(src, &Bs[brow * 64]);
    }
    // A tile: gathered rows, reg-staged
#pragma unroll
    for (int i = 0; i < 4; ++i) {
      const bf16x8 v = *reinterpret_cast<const bf16x8*>(aptr[i] + k0);
      *reinterpret_cast<bf16x8*>(&As[((size_t)(i * 32 + (tid >> 3))) * 72 + (tid & 7) * 8]) = v;
    }
    __syncthreads();
#pragma unroll
    for (int kk = 0; kk < 2; ++kk) {
      bf16x8 af[4], bfr[4];
#pragma unroll
      for (int fm = 0; fm < 4; ++fm)
        af[fm] = *reinterpret_cast<const bf16x8*>(
            &As[(wr * 64 + fm * 16 + (lane & 15)) * 72 + kk * 32 + (lane >> 4) * 8]);
#pragma unroll
      for (int fn = 0; fn < 4; ++fn)
        bfr[fn] = *reinterpret_cast<const bf16x8*>(
            &Bs[(wc * 64 + fn * 16 + (lane & 15)) * 64 + kk * 32 + (lane >> 4) * 8]);
#pragma unroll
      for (int fm = 0; fm < 4; ++fm)
#pragma unroll
        for (int fn = 0; fn < 4; ++fn)
          acc[fm][fn] = __builtin_amdgcn_mfma_f32_16x16x32_bf16(af[fm], bfr[fn],
                                                                acc[fm][fn], 0, 0, 0);
    }
    __syncthreads();
  }

  const float* bias_e = bias + (size_t)e * NT;
#pragma unroll
  for (int fm = 0; fm < 4; ++fm) {
#pragma unroll
    for (int r = 0; r < 4; ++r) {
      const int row = wr * 64 + fm * 16 + (lane >> 4) * 4 + r;
      if (m0 + row >= cnt) continue;
      const int p = rowp[row];
#pragma unroll
      for (int fn = 0; fn < 4; ++fn) {
        const int n = n0 + wc * 64 + fn * 16 + (lane & 15);
        const float v = acc[fm][fn][r] + bias_e[n];
        if (PHASE == 1) {
          const float g = 0.5f * v * (1.0f + erff(v * 0.70710678118654752f));
          hout[(size_t)p * NT + n] = f2bf(g);
        } else if (PHASE == 2) {
          yout[(size_t)p * NT + n] = gate_p[p] * v;
        } else {
          atomicAdd(&yout[(size_t)(p >> 1) * NT + n], gate_p[p] * v);
        }
      }
    }
  }
}

// ---------------- combine the two pair rows per token ------------------------
__global__ void combine_kernel(const float* __restrict__ yp, float* __restrict__ out) {
  const int i = blockIdx.x * blockDim.x + threadIdx.x;  // over T*D/4
  const int t = i >> 8;        // D/4 = 256 float4 per row
  const int d4 = i & 255;
  const float4 a = reinterpret_cast<const float4*>(yp)[(size_t)(2 * t) * 256 + d4];
  const float4 b = reinterpret_cast<const float4*>(yp)[(size_t)(2 * t) * 256 + 256 + d4];
  float4 o; o.x = a.x + b.x; o.y = a.y + b.y; o.z = a.z + b.z; o.w = a.w + b.w;
  reinterpret_cast<float4*>(out)[i] = o;
}

extern "C" void kernel_launch(void* const* d_in, const int* in_sizes, int n_in,
                              void* d_out, int out_size, void* d_ws, size_t ws_size,
                              hipStream_t stream) {
  const float* x  = (const float*)d_in[0];
  const float* Wr = (const float*)d_in[1];
  const float* br = (const float*)d_in[2];
  const float* gb = (const float*)d_in[3];
  const float* W1 = (const float*)d_in[4];
  const float* b1 = (const float*)d_in[5];
  const float* W2 = (const float*)d_in[6];
  const float* b2 = (const float*)d_in[7];
  float* out = (float*)d_out;

  char* ws = (char*)d_ws;
  size_t off = 0;
  int*   counts = (int*)(ws + off);   off += 256;
  int*   lists  = (int*)(ws + off);   off += (size_t)NE * T_TOK * 4;      // 128 KB
  float* gate_p = (float*)(ws + off); off += (size_t)T_TOK * 2 * 4;       // 32 KB
  u16*   xb     = (u16*)(ws + off);   off += (size_t)T_TOK * DIM * 2;     // 8 MB
  u16*   wbuf   = (u16*)(ws + off);   off += (size_t)NE * DIM * HID * 2;  // 64 MB (reused W1t then W2t)
  u16*   hbuf   = (u16*)(ws + off);   off += (size_t)T_TOK * 2 * HID * 2; // 64 MB
  const size_t need_base = off;
  float* ypair  = (float*)(ws + off);
  const size_t need_full = off + (size_t)T_TOK * 2 * DIM * 4;             // +32 MB
  const bool use_ypair = (ws_size >= need_full);
  (void)need_base;

  hipMemsetAsync(counts, 0, 32, stream);
  router_kernel<<<T_TOK / 4, 256, 0, stream>>>(x, Wr, br, gb, counts, lists, gate_p);
  cvt_x_kernel<<<(T_TOK * DIM / 8 + 255) / 256, 256, 0, stream>>>(x, xb, T_TOK * DIM / 8);
  cvt_w_kernel<<<dim3(HID / 64, DIM / 64, NE), 256, 0, stream>>>(W1, wbuf, DIM, HID);
  gemm_kernel<DIM, HID, 1><<<dim3(HID / 128, T_TOK / 128, NE), 256, 0, stream>>>(
      xb, wbuf, b1, counts, lists, gate_p, hbuf, nullptr);
  cvt_w_kernel<<<dim3(DIM / 64, HID / 64, NE), 256, 0, stream>>>(W2, wbuf, HID, DIM);
  if (use_ypair) {
    gemm_kernel<HID, DIM, 2><<<dim3(DIM / 128, T_TOK / 128, NE), 256, 0, stream>>>(
        hbuf, wbuf, b2, counts, lists, gate_p, nullptr, ypair);
    combine_kernel<<<T_TOK, 256, 0, stream>>>(ypair, out);
  } else {
    hipMemsetAsync(out, 0, (size_t)out_size * 4, stream);
    gemm_kernel<HID, DIM, 3><<<dim3(DIM / 128, T_TOK / 128, NE), 256, 0, stream>>>(
        hbuf, wbuf, b2, counts, lists, gate_p, nullptr, out);
  }
}